// Round 13
// baseline (71.277 us; speedup 1.0000x reference)
//
#include <hip/hip_runtime.h>

#define NN 8192
#define DD 256    // 256 bytes per fp8 row
#define NTILES 2080
#define NBLK 768

typedef float f32x4 __attribute__((ext_vector_type(4)));

__device__ __forceinline__ void gload16(const void* g, void* l) {
    __builtin_amdgcn_global_load_lds((const __attribute__((address_space(1))) void*)g,
                                     (__attribute__((address_space(3))) void*)l,
                                     16, 0, 0);
}

// ---------------- kernel 1: normalize rows -> fp8 e4m3, zero accumulators ----------------
__global__ __launch_bounds__(256) void ntxent_norm(const float* __restrict__ z,
                                                   char* __restrict__ zn8,
                                                   float* __restrict__ rowsum,
                                                   float* __restrict__ possum)
{
    const int t = threadIdx.x;
    const int l = t & 63;
    const int w = t >> 6;
    const int row = blockIdx.x * 4 + w;

    float4 v = ((const float4*)(z + (size_t)row * DD))[l];
    float ss = v.x * v.x + v.y * v.y + v.z * v.z + v.w * v.w;
    ss += __shfl_xor(ss, 1);  ss += __shfl_xor(ss, 2);  ss += __shfl_xor(ss, 4);
    ss += __shfl_xor(ss, 8);  ss += __shfl_xor(ss, 16); ss += __shfl_xor(ss, 32);
    const float inv = 1.0f / fmaxf(sqrtf(ss), 1e-8f);

    int u = __builtin_amdgcn_cvt_pk_fp8_f32(v.x * inv, v.y * inv, 0, false);
    u     = __builtin_amdgcn_cvt_pk_fp8_f32(v.z * inv, v.w * inv, u, true);
    ((int*)(zn8 + (size_t)row * 256))[l] = u;

    if (blockIdx.x < 32) rowsum[blockIdx.x * 256 + t] = 0.0f;
    if (blockIdx.x == 32 && t == 0) possum[0] = 0.0f;
}

// ---------------- kernel 2: fp8 triangle, R7 continuous 2-phase pipeline ----------------
// 2080 lower-triangle 128x128 tiles; 768 blocks (3/CU resident), contiguous runs of 2-3.
// BK=64 fp8 chunk = 128 rows x 128B [A 64B | B 64B], 8 x 16B units, XOR involution
// u_phys = u_log ^ (row&7) across the A|B interleave (R8-validated numerically;
// A/B reads: 8 distinct units, 2 lanes each = 2-way = free per m136).
// Double-buffered 2x16KB = 33KB LDS -> 4 blocks/CU by LDS; ~140 unified regs -> 3/CU.
// Per K-step: issue STAGE(next) FIRST, 32 fp8 MFMAs (same count as R7, half the bytes),
// ONE vmcnt(0)+barrier. Pipeline continuous across tiles (R7's proven discipline).
// Epilogue per tile = R7 verbatim: exp, rsum row-reduce + atomics, csum col flush
// (symmetry), diag self-mask + positives.
__global__ __launch_bounds__(256) void ntxent_sim(const char* __restrict__ zn8,
                                                  float* __restrict__ rowsum,
                                                  float* __restrict__ possum)
{
    __shared__ char sAB[2][16384];   // [buf][128 rows x 128B (A|B interleave)], swizzled
    __shared__ float psh[4];

    const int t  = threadIdx.x;
    const int l  = t & 63;
    const int w  = t >> 6;      // wave 0..3
    const int wr = w >> 1;      // row half
    const int wc = w & 1;       // col half
    const int lm = l & 15;
    const int lh = l >> 4;      // 0..3

    const int arow0 = wr * 64;
    const int bcol0 = wc * 64;
    const f32x4 vzero = {0.0f, 0.0f, 0.0f, 0.0f};

    // contiguous tile range [t0, t1)
    const int t0 = (NTILES * blockIdx.x) / NBLK;
    const int t1 = (NTILES * (blockIdx.x + 1)) / NBLK;

    int rt = (int)((sqrtf(8.0f * (float)t0 + 1.0f) - 1.0f) * 0.5f);
    while ((rt + 1) * (rt + 2) / 2 <= t0) ++rt;
    while (rt * (rt + 1) / 2 > t0) --rt;
    int ct = t0 - rt * (rt + 1) / 2;

    // stage BK=64 chunk bk of tile (rowbase,colbase) into buffer: 4 x gload16/thread
    auto STAGE = [&](int buf, int rowbase, int colbase, int bk) {
#pragma unroll
        for (int p = 0; p < 4; ++p) {
            const int flat = p * 4096 + t * 16;
            const int r = flat >> 7;                 // 0..127
            const int d = (flat >> 4) & 7;           // physical 16B unit
            const int s = d ^ (r & 7);               // logical unit (involution)
            const char* src = (s < 4)
                ? zn8 + (size_t)(rowbase + r) * 256 + bk * 64 + s * 16
                : zn8 + (size_t)(colbase + r) * 256 + bk * 64 + (s - 4) * 16;
            gload16(src, &sAB[buf][flat]);
        }
    };

    int buf = 0;
    STAGE(0, rt * 128, ct * 128, 0);
    asm volatile("s_waitcnt vmcnt(0)" ::: "memory");
    __syncthreads();

#pragma unroll 1
    for (int tl = t0; tl < t1; ++tl) {
        const int rowbase = rt * 128;
        const int colbase = ct * 128;
        const bool diag = (rt == ct);
        const int nrt = (ct < rt) ? rt : rt + 1;     // next triangle tile
        const int nct = (ct < rt) ? ct + 1 : 0;

        f32x4 acc[4][4];
#pragma unroll
        for (int r = 0; r < 4; ++r)
#pragma unroll
            for (int c = 0; c < 4; ++c) acc[r][c] = vzero;

#pragma unroll 1
        for (int bk = 0; bk < 4; ++bk) {
            // issue next chunk's stage BEFORE computing current chunk
            if (bk < 3)            STAGE(buf ^ 1, rowbase, colbase, bk + 1);
            else if (tl + 1 < t1)  STAGE(buf ^ 1, nrt * 128, nct * 128, 0);

            const char* bb = sAB[buf];
#pragma unroll
            for (int chunk = 0; chunk < 2; ++chunk) {
                long af[4], bfr[4];
#pragma unroll
                for (int s = 0; s < 4; ++s) {
                    const int ar = arow0 + s * 16 + lm;
                    const int ua = (chunk * 2 + (lh >> 1)) ^ (ar & 7);
                    af[s] = *(const long*)(bb + ar * 128 + (ua << 4) + ((lh & 1) << 3));
                    const int bc = bcol0 + s * 16 + lm;
                    const int ub = (4 + chunk * 2 + (lh >> 1)) ^ (bc & 7);
                    bfr[s] = *(const long*)(bb + bc * 128 + (ub << 4) + ((lh & 1) << 3));
                }
#pragma unroll
                for (int r = 0; r < 4; ++r)
#pragma unroll
                    for (int c = 0; c < 4; ++c)
                        acc[r][c] = __builtin_amdgcn_mfma_f32_16x16x32_fp8_fp8(af[r], bfr[c], acc[r][c], 0, 0, 0);
            }

            asm volatile("s_waitcnt vmcnt(0)" ::: "memory");
            __syncthreads();
            buf ^= 1;
        }

        // ---------------- epilogue: exp, row sums, col sums (symmetry), positives ----
        float rsum[16];
#pragma unroll
        for (int q = 0; q < 16; ++q) rsum[q] = 0.0f;
        float csum[4] = {0.0f, 0.0f, 0.0f, 0.0f};
        float psum = 0.0f;

#pragma unroll
        for (int r = 0; r < 4; ++r) {
            const int ib = rowbase + arow0 + r * 16 + lh * 4;
#pragma unroll
            for (int c = 0; c < 4; ++c) {
                const int j = colbase + bcol0 + c * 16 + lm;
#pragma unroll
                for (int q = 0; q < 4; ++q) {
                    const int i = ib + q;
                    const float lg = 2.0f * acc[r][c][q];
                    const float e = __expf(lg);
                    const float ev = (diag && (j == i)) ? 0.0f : e;
                    rsum[r * 4 + q] += ev;
                    csum[c] += ev;                                   // used iff !diag
                    if (diag) psum += (j == (i ^ 1)) ? lg : 0.0f;
                }
            }
        }

        // row sums: reduce over the 16 lm lanes, one atomic per row
#pragma unroll
        for (int q = 0; q < 16; ++q) {
            float v = rsum[q];
            v += __shfl_xor(v, 1); v += __shfl_xor(v, 2);
            v += __shfl_xor(v, 4); v += __shfl_xor(v, 8);
            rsum[q] = v;
        }
        if (lm == 0) {
#pragma unroll
            for (int r = 0; r < 4; ++r)
#pragma unroll
                for (int q = 0; q < 4; ++q)
                    atomicAdd(&rowsum[rowbase + arow0 + r * 16 + lh * 4 + q], rsum[r * 4 + q]);
        }

        if (!diag) {
            // col sums (transposed contribution): collapse lh groups, atomic per col
#pragma unroll
            for (int c = 0; c < 4; ++c) {
                float v = csum[c];
                v += __shfl_xor(v, 16); v += __shfl_xor(v, 32);
                if (lh == 0) atomicAdd(&rowsum[colbase + bcol0 + c * 16 + lm], v);
            }
        } else {
            // positive-pair block reduce -> possum[0]
            float p = psum;
            p += __shfl_xor(p, 1);  p += __shfl_xor(p, 2);  p += __shfl_xor(p, 4);
            p += __shfl_xor(p, 8);  p += __shfl_xor(p, 16); p += __shfl_xor(p, 32);
            if (l == 0) psh[w] = p;
            __syncthreads();
            if (t == 0) atomicAdd(possum, psh[0] + psh[1] + psh[2] + psh[3]);
            __syncthreads();   // protect psh before any later diag tile reuses it
        }

        rt = nrt; ct = nct;
    }
}

// ---------------- kernel 3: final scalar ----------------
__global__ __launch_bounds__(512) void ntxent_final(const float* __restrict__ rowsum,
                                                    const float* __restrict__ possum,
                                                    float* __restrict__ out)
{
    __shared__ float sh[8];
    const int t = threadIdx.x;
    float s = 0.0f;
#pragma unroll
    for (int r = 0; r < 16; ++r) s += __logf(rowsum[r * 512 + t]);  // ILP: 16 indep loads
    s += __shfl_xor(s, 1);  s += __shfl_xor(s, 2);  s += __shfl_xor(s, 4);
    s += __shfl_xor(s, 8);  s += __shfl_xor(s, 16); s += __shfl_xor(s, 32);
    if ((t & 63) == 0) sh[t >> 6] = s;
    __syncthreads();
    if (t == 0) {
        float a = 0.0f;
#pragma unroll
        for (int k = 0; k < 8; ++k) a += sh[k];
        out[0] = (a - possum[0]) * (1.0f / NN);
    }
}

extern "C" void kernel_launch(void* const* d_in, const int* in_sizes, int n_in,
                              void* d_out, int out_size, void* d_ws, size_t ws_size,
                              hipStream_t stream)
{
    const float* z = (const float*)d_in[0];
    char*  zn8    = (char*)d_ws;                                      // 2 MB fp8
    float* rowsum = (float*)((char*)d_ws + (size_t)NN * 256);         // 32 KB
    float* possum = (float*)((char*)d_ws + (size_t)NN * 256 + (size_t)NN * 4);
    float* out = (float*)d_out;

    ntxent_norm <<<dim3(NN / 4), dim3(256), 0, stream>>>(z, zn8, rowsum, possum);
    ntxent_sim  <<<dim3(NBLK),   dim3(256), 0, stream>>>(zn8, rowsum, possum);
    ntxent_final<<<dim3(1),      dim3(512), 0, stream>>>(rowsum, possum, out);
}

// Round 14
// 68.768 us; speedup vs baseline: 1.0365x; 1.0365x over previous
//
#include <hip/hip_runtime.h>

#define NN 8192
#define DD 256   // 512 bytes per bf16 row
#define NTILES 2080
#define NBLK 512

typedef __bf16 bf16x8 __attribute__((ext_vector_type(8)));
typedef float  f32x4  __attribute__((ext_vector_type(4)));

__device__ __forceinline__ unsigned short f2bf(float f) {
    unsigned u = __float_as_uint(f);
    return (unsigned short)((u + 0x7fffu + ((u >> 16) & 1u)) >> 16);
}

__device__ __forceinline__ void gload16(const void* g, void* l) {
    __builtin_amdgcn_global_load_lds((const __attribute__((address_space(1))) void*)g,
                                     (__attribute__((address_space(3))) void*)l,
                                     16, 0, 0);
}

// ---------------- kernel 1: normalize rows -> bf16, zero accumulators ----------------
__global__ __launch_bounds__(256) void ntxent_norm(const float* __restrict__ z,
                                                   char* __restrict__ znB,
                                                   float* __restrict__ rowsum,
                                                   float* __restrict__ possum)
{
    const int t = threadIdx.x;
    const int l = t & 63;
    const int w = t >> 6;
    const int row = blockIdx.x * 4 + w;

    float4 v = ((const float4*)(z + (size_t)row * DD))[l];
    float ss = v.x * v.x + v.y * v.y + v.z * v.z + v.w * v.w;
    ss += __shfl_xor(ss, 1);  ss += __shfl_xor(ss, 2);  ss += __shfl_xor(ss, 4);
    ss += __shfl_xor(ss, 8);  ss += __shfl_xor(ss, 16); ss += __shfl_xor(ss, 32);
    const float inv = 1.0f / fmaxf(sqrtf(ss), 1e-8f);

    uint2 o;
    o.x = (unsigned)f2bf(v.x * inv) | ((unsigned)f2bf(v.y * inv) << 16);
    o.y = (unsigned)f2bf(v.z * inv) | ((unsigned)f2bf(v.w * inv) << 16);
    ((uint2*)(znB + (size_t)row * 512))[l] = o;

    if (blockIdx.x < 32) rowsum[blockIdx.x * 256 + t] = 0.0f;
    if (blockIdx.x == 32 && t == 0) possum[0] = 0.0f;
}

// ---------------- kernel 2: R7 pipeline + deferred reductions + XCD swizzle ----------
// Base = R7 (measured champion, 45.4 us): 2080 triangle tiles, 512 blocks x runs of
// 4-5, double-buffered LDS, STAGE(next) issued BEFORE compute, ONE vmcnt(0)+barrier
// per K-step, continuous across tiles, XOR swizzle (0 conflicts measured).
// Surgical edits only:
//  (1) rsum[16] persists across the run; heavy 64-shfl reduce + row atomics fire only
//      when rt changes or at run end (R1's cadence, proven cheaper). psum likewise:
//      one wave-reduce + predicated atomic at the very end; diag path loses its 2
//      extra __syncthreads + psh buffer.
//  (2) XCD-aware run assignment: sb = (bid&7)*64 + bid/8 (bijective, 512=8x64) so
//      each XCD's blocks cover a contiguous triangle region (A-panel L2 reuse).
__global__ __launch_bounds__(256) void ntxent_sim(const char* __restrict__ znB,
                                                  float* __restrict__ rowsum,
                                                  float* __restrict__ possum)
{
    __shared__ char sA[2][16384];   // 128 rows x 128B (BK=64), XOR-swizzled
    __shared__ char sB[2][16384];

    const int t  = threadIdx.x;
    const int l  = t & 63;
    const int w  = t >> 6;      // wave 0..3
    const int wr = w >> 1;      // row half
    const int wc = w & 1;       // col half
    const int lm = l & 15;
    const int lh = l >> 4;      // 0..3

    const int arow0 = wr * 64;
    const int bcol0 = wc * 64;
    const f32x4 vzero = {0.0f, 0.0f, 0.0f, 0.0f};

    // XCD-contiguous run id (bijective permutation of 0..511)
    const int sb = ((blockIdx.x & 7) << 6) | (blockIdx.x >> 3);

    // contiguous tile range [t0, t1) for this run
    const int t0 = (NTILES * sb) >> 9;
    const int t1 = (NTILES * (sb + 1)) >> 9;

    // t0 -> (rt, ct), rt >= ct
    int rt = (int)((sqrtf(8.0f * (float)t0 + 1.0f) - 1.0f) * 0.5f);
    while ((rt + 1) * (rt + 2) / 2 <= t0) ++rt;
    while (rt * (rt + 1) / 2 > t0) --rt;
    int ct = t0 - rt * (rt + 1) / 2;

    auto STAGE = [&](int buf, int rowbase, int colbase, int bk) {
#pragma unroll
        for (int p = 0; p < 4; ++p) {
            const int flat = p * 4096 + t * 16;
            const int row = flat >> 7;
            const int kb  = flat & 127;
            const int skb = (kb ^ ((row & 7) << 4));
            gload16(znB + (size_t)(rowbase + row) * 512 + bk * 128 + skb, &sA[buf][flat]);
            gload16(znB + (size_t)(colbase + row) * 512 + bk * 128 + skb, &sB[buf][flat]);
        }
    };

    int buf = 0;
    STAGE(0, rt * 128, ct * 128, 0);
    asm volatile("s_waitcnt vmcnt(0)" ::: "memory");
    __syncthreads();

    float rsum[16];
#pragma unroll
    for (int q = 0; q < 16; ++q) rsum[q] = 0.0f;
    float psum = 0.0f;

#pragma unroll 1
    for (int tl = t0; tl < t1; ++tl) {
        const int rowbase = rt * 128;
        const int colbase = ct * 128;
        const bool diag = (rt == ct);
        const int nrt = (ct < rt) ? rt : rt + 1;   // next tile (triangle walk)
        const int nct = (ct < rt) ? ct + 1 : 0;

        f32x4 acc[4][4];
#pragma unroll
        for (int r = 0; r < 4; ++r)
#pragma unroll
            for (int c = 0; c < 4; ++c) acc[r][c] = vzero;

#pragma unroll 1
        for (int bk = 0; bk < 4; ++bk) {
            // issue next chunk's stage BEFORE computing current chunk
            if (bk < 3)            STAGE(buf ^ 1, rowbase, colbase, bk + 1);
            else if (tl + 1 < t1)  STAGE(buf ^ 1, nrt * 128, nct * 128, 0);

#pragma unroll
            for (int kw = 0; kw < 2; ++kw) {
                const int kt = kw * 64 + lh * 16;
                bf16x8 af[4], bfr[4];
#pragma unroll
                for (int s = 0; s < 4; ++s) {
                    const int ar = arow0 + s * 16 + lm;
                    af[s]  = *(const bf16x8*)(&sA[buf][ar * 128 + (kt ^ ((ar & 7) << 4))]);
                    const int bc = bcol0 + s * 16 + lm;
                    bfr[s] = *(const bf16x8*)(&sB[buf][bc * 128 + (kt ^ ((bc & 7) << 4))]);
                }
#pragma unroll
                for (int r = 0; r < 4; ++r)
#pragma unroll
                    for (int c = 0; c < 4; ++c)
                        acc[r][c] = __builtin_amdgcn_mfma_f32_16x16x32_bf16(af[r], bfr[c], acc[r][c], 0, 0, 0);
            }

            // single drain: my loads done -> barrier -> staged buf^1 visible to all
            asm volatile("s_waitcnt vmcnt(0)" ::: "memory");
            __syncthreads();
            buf ^= 1;
        }

        // ---- per-tile epilogue (cheap): exp into persistent rsum; csum col flush ----
        float csum[4] = {0.0f, 0.0f, 0.0f, 0.0f};
#pragma unroll
        for (int r = 0; r < 4; ++r) {
            const int ib = rowbase + arow0 + r * 16 + lh * 4;
#pragma unroll
            for (int c = 0; c < 4; ++c) {
                const int j = colbase + bcol0 + c * 16 + lm;
#pragma unroll
                for (int q = 0; q < 4; ++q) {
                    const int i = ib + q;
                    const float lg = 2.0f * acc[r][c][q];
                    const float e = __expf(lg);
                    const float ev = (diag && (j == i)) ? 0.0f : e;
                    rsum[r * 4 + q] += ev;
                    csum[c] += ev;                                   // used iff !diag
                    if (diag) psum += (j == (i ^ 1)) ? lg : 0.0f;
                }
            }
        }
        if (!diag) {
            // transposed contribution: collapse lh groups, one atomic per col (lh==0)
#pragma unroll
            for (int c = 0; c < 4; ++c) {
                float v = csum[c];
                v += __shfl_xor(v, 16); v += __shfl_xor(v, 32);
                if (lh == 0) atomicAdd(&rowsum[colbase + bcol0 + c * 16 + lm], v);
            }
        }

        // ---- deferred heavy row reduce: only when rt changes or run ends ----
        if (tl + 1 == t1 || nrt != rt) {
#pragma unroll
            for (int q = 0; q < 16; ++q) {
                float v = rsum[q];
                v += __shfl_xor(v, 1); v += __shfl_xor(v, 2);
                v += __shfl_xor(v, 4); v += __shfl_xor(v, 8);
                rsum[q] = v;
            }
            if (lm == 0) {
#pragma unroll
                for (int r = 0; r < 4; ++r)
#pragma unroll
                    for (int q = 0; q < 4; ++q)
                        atomicAdd(&rowsum[rowbase + arow0 + r * 16 + lh * 4 + q], rsum[r * 4 + q]);
            }
#pragma unroll
            for (int q = 0; q < 16; ++q) rsum[q] = 0.0f;
        }

        rt = nrt; ct = nct;
    }

    // ---- deferred positive-pair flush (once per block; nonzero only for diag runs) ----
    psum += __shfl_xor(psum, 1);  psum += __shfl_xor(psum, 2);  psum += __shfl_xor(psum, 4);
    psum += __shfl_xor(psum, 8);  psum += __shfl_xor(psum, 16); psum += __shfl_xor(psum, 32);
    if (l == 0 && psum != 0.0f) atomicAdd(possum, psum);
}

// ---------------- kernel 3: final scalar ----------------
__global__ __launch_bounds__(512) void ntxent_final(const float* __restrict__ rowsum,
                                                    const float* __restrict__ possum,
                                                    float* __restrict__ out)
{
    __shared__ float sh[8];
    const int t = threadIdx.x;
    float s = 0.0f;
#pragma unroll
    for (int r = 0; r < 16; ++r) s += __logf(rowsum[r * 512 + t]);  // ILP: 16 indep loads
    s += __shfl_xor(s, 1);  s += __shfl_xor(s, 2);  s += __shfl_xor(s, 4);
    s += __shfl_xor(s, 8);  s += __shfl_xor(s, 16); s += __shfl_xor(s, 32);
    if ((t & 63) == 0) sh[t >> 6] = s;
    __syncthreads();
    if (t == 0) {
        float a = 0.0f;
#pragma unroll
        for (int k = 0; k < 8; ++k) a += sh[k];
        out[0] = (a - possum[0]) * (1.0f / NN);
    }
}

extern "C" void kernel_launch(void* const* d_in, const int* in_sizes, int n_in,
                              void* d_out, int out_size, void* d_ws, size_t ws_size,
                              hipStream_t stream)
{
    const float* z = (const float*)d_in[0];
    char*  znB    = (char*)d_ws;
    float* rowsum = (float*)((char*)d_ws + (size_t)NN * 512);
    float* possum = (float*)((char*)d_ws + (size_t)NN * 512 + (size_t)NN * 4);
    float* out = (float*)d_out;

    ntxent_norm <<<dim3(NN / 4), dim3(256), 0, stream>>>(z, znB, rowsum, possum);
    ntxent_sim  <<<dim3(NBLK),   dim3(256), 0, stream>>>(znB, rowsum, possum);
    ntxent_final<<<dim3(1),      dim3(512), 0, stream>>>(rowsum, possum, out);
}

// Round 15
// 66.265 us; speedup vs baseline: 1.0756x; 1.0378x over previous
//
#include <hip/hip_runtime.h>

#define NN 8192
#define DD 256   // 512 bytes per bf16 row
#define NTILES 2080
#define NBLK 512

typedef __bf16 bf16x8 __attribute__((ext_vector_type(8)));
typedef float  f32x4  __attribute__((ext_vector_type(4)));

__device__ __forceinline__ unsigned short f2bf(float f) {
    unsigned u = __float_as_uint(f);
    return (unsigned short)((u + 0x7fffu + ((u >> 16) & 1u)) >> 16);
}

__device__ __forceinline__ void gload16(const void* g, void* l) {
    __builtin_amdgcn_global_load_lds((const __attribute__((address_space(1))) void*)g,
                                     (__attribute__((address_space(3))) void*)l,
                                     16, 0, 0);
}

// ---------------- kernel 1: normalize rows -> bf16, zero accumulators ----------------
__global__ __launch_bounds__(256) void ntxent_norm(const float* __restrict__ z,
                                                   char* __restrict__ znB,
                                                   float* __restrict__ rowsum,
                                                   float* __restrict__ possum)
{
    const int t = threadIdx.x;
    const int l = t & 63;
    const int w = t >> 6;
    const int row = blockIdx.x * 4 + w;

    float4 v = ((const float4*)(z + (size_t)row * DD))[l];
    float ss = v.x * v.x + v.y * v.y + v.z * v.z + v.w * v.w;
    ss += __shfl_xor(ss, 1);  ss += __shfl_xor(ss, 2);  ss += __shfl_xor(ss, 4);
    ss += __shfl_xor(ss, 8);  ss += __shfl_xor(ss, 16); ss += __shfl_xor(ss, 32);
    const float inv = 1.0f / fmaxf(sqrtf(ss), 1e-8f);

    uint2 o;
    o.x = (unsigned)f2bf(v.x * inv) | ((unsigned)f2bf(v.y * inv) << 16);
    o.y = (unsigned)f2bf(v.z * inv) | ((unsigned)f2bf(v.w * inv) << 16);
    ((uint2*)(znB + (size_t)row * 512))[l] = o;

    if (blockIdx.x < 32) rowsum[blockIdx.x * 256 + t] = 0.0f;
    if (blockIdx.x == 32 && t == 0) possum[0] = 0.0f;
}

// ---------------- kernel 2: R7 pipeline, 8 thin waves (64x32 wave tiles) ----------------
// R7's champion structure verbatim (2080 triangle tiles, runs of 4-5, double-buffered
// LDS, STAGE(next) BEFORE compute, ONE vmcnt(0)+barrier per K-step, continuous across
// tiles, XOR swizzle) with ONE change: 512 threads = 8 waves of 64x32 tiles instead of
// 4 waves of 64x64. Per-wave unified regs drop ~180 -> ~100 (acc[4][2]=32 AGPR,
// af[4]+bfr[2]=24 VGPR) -> 4 waves/SIMD -> 16 waves/CU resident (2 blocks x 8) vs
// R7's 8. Cross-round law: step rate scales with resident waves; predict ~2x.
// rsum stays tile-local (R14 taught: live-across-K-loop costs 20 VGPR). psum flushed
// once at kernel end (no psh, no extra barriers).
__global__ __launch_bounds__(512) void ntxent_sim(const char* __restrict__ znB,
                                                  float* __restrict__ rowsum,
                                                  float* __restrict__ possum)
{
    __shared__ char sA[2][16384];   // 128 rows x 128B (BK=64), XOR-swizzled
    __shared__ char sB[2][16384];

    const int t  = threadIdx.x;
    const int l  = t & 63;
    const int w  = t >> 6;      // wave 0..7
    const int wr = w >> 2;      // row half (64 rows)
    const int wc = w & 3;       // col quarter (32 cols)
    const int lm = l & 15;
    const int lh = l >> 4;      // 0..3

    const int arow0 = wr * 64;
    const int bcol0 = wc * 32;
    const f32x4 vzero = {0.0f, 0.0f, 0.0f, 0.0f};

    // contiguous tile range [t0, t1) for this block
    const int t0 = (NTILES * blockIdx.x) >> 9;
    const int t1 = (NTILES * (blockIdx.x + 1)) >> 9;

    // t0 -> (rt, ct), rt >= ct
    int rt = (int)((sqrtf(8.0f * (float)t0 + 1.0f) - 1.0f) * 0.5f);
    while ((rt + 1) * (rt + 2) / 2 <= t0) ++rt;
    while (rt * (rt + 1) / 2 > t0) --rt;
    int ct = t0 - rt * (rt + 1) / 2;

    auto STAGE = [&](int buf, int rowbase, int colbase, int bk) {
#pragma unroll
        for (int p = 0; p < 2; ++p) {
            const int flat = p * 8192 + t * 16;
            const int row = flat >> 7;
            const int kb  = flat & 127;
            const int skb = (kb ^ ((row & 7) << 4));
            gload16(znB + (size_t)(rowbase + row) * 512 + bk * 128 + skb, &sA[buf][flat]);
            gload16(znB + (size_t)(colbase + row) * 512 + bk * 128 + skb, &sB[buf][flat]);
        }
    };

    int buf = 0;
    STAGE(0, rt * 128, ct * 128, 0);
    asm volatile("s_waitcnt vmcnt(0)" ::: "memory");
    __syncthreads();

    float psum = 0.0f;

#pragma unroll 1
    for (int tl = t0; tl < t1; ++tl) {
        const int rowbase = rt * 128;
        const int colbase = ct * 128;
        const bool diag = (rt == ct);
        const int nrt = (ct < rt) ? rt : rt + 1;   // next tile (triangle walk)
        const int nct = (ct < rt) ? ct + 1 : 0;

        f32x4 acc[4][2];
#pragma unroll
        for (int s = 0; s < 4; ++s) { acc[s][0] = vzero; acc[s][1] = vzero; }

#pragma unroll 1
        for (int bk = 0; bk < 4; ++bk) {
            // issue next chunk's stage BEFORE computing current chunk
            if (bk < 3)            STAGE(buf ^ 1, rowbase, colbase, bk + 1);
            else if (tl + 1 < t1)  STAGE(buf ^ 1, nrt * 128, nct * 128, 0);

#pragma unroll
            for (int kw = 0; kw < 2; ++kw) {
                const int kt = kw * 64 + lh * 16;
                bf16x8 af[4], bfr[2];
#pragma unroll
                for (int s = 0; s < 4; ++s) {
                    const int ar = arow0 + s * 16 + lm;
                    af[s] = *(const bf16x8*)(&sA[buf][ar * 128 + (kt ^ ((ar & 7) << 4))]);
                }
#pragma unroll
                for (int c = 0; c < 2; ++c) {
                    const int bc = bcol0 + c * 16 + lm;
                    bfr[c] = *(const bf16x8*)(&sB[buf][bc * 128 + (kt ^ ((bc & 7) << 4))]);
                }
#pragma unroll
                for (int s = 0; s < 4; ++s) {
                    acc[s][0] = __builtin_amdgcn_mfma_f32_16x16x32_bf16(af[s], bfr[0], acc[s][0], 0, 0, 0);
                    acc[s][1] = __builtin_amdgcn_mfma_f32_16x16x32_bf16(af[s], bfr[1], acc[s][1], 0, 0, 0);
                }
            }

            // single drain: my loads done -> barrier -> staged buf^1 visible to all
            asm volatile("s_waitcnt vmcnt(0)" ::: "memory");
            __syncthreads();
            buf ^= 1;
        }

        // ---- per-tile epilogue (R7 cadence): exp, rsum reduce+atomics, csum flush ----
        float rsum[16];
#pragma unroll
        for (int q = 0; q < 16; ++q) rsum[q] = 0.0f;
        float csum[2] = {0.0f, 0.0f};

#pragma unroll
        for (int s = 0; s < 4; ++s) {
            const int ib = rowbase + arow0 + s * 16 + lh * 4;
#pragma unroll
            for (int c = 0; c < 2; ++c) {
                const int j = colbase + bcol0 + c * 16 + lm;
#pragma unroll
                for (int q = 0; q < 4; ++q) {
                    const int i = ib + q;
                    const float lg = 2.0f * acc[s][c][q];
                    const float e = __expf(lg);
                    const float ev = (diag && (j == i)) ? 0.0f : e;
                    rsum[s * 4 + q] += ev;
                    csum[c] += ev;                                   // used iff !diag
                    if (diag) psum += (j == (i ^ 1)) ? lg : 0.0f;
                }
            }
        }

        // row sums: reduce over the 16 lm lanes, one atomic per row (lm==0)
#pragma unroll
        for (int q = 0; q < 16; ++q) {
            float v = rsum[q];
            v += __shfl_xor(v, 1); v += __shfl_xor(v, 2);
            v += __shfl_xor(v, 4); v += __shfl_xor(v, 8);
            rsum[q] = v;
        }
        if (lm == 0) {
#pragma unroll
            for (int s = 0; s < 4; ++s)
#pragma unroll
                for (int q = 0; q < 4; ++q)
                    atomicAdd(&rowsum[rowbase + arow0 + s * 16 + lh * 4 + q], rsum[s * 4 + q]);
        }

        if (!diag) {
            // col sums (transposed contribution): collapse lh, one atomic per col (lh==0)
#pragma unroll
            for (int c = 0; c < 2; ++c) {
                float v = csum[c];
                v += __shfl_xor(v, 16); v += __shfl_xor(v, 32);
                if (lh == 0) atomicAdd(&rowsum[colbase + bcol0 + c * 16 + lm], v);
            }
        }

        rt = nrt; ct = nct;
    }

    // ---- positive-pair flush: once per kernel, per-wave reduce + one atomic ----
    psum += __shfl_xor(psum, 1);  psum += __shfl_xor(psum, 2);  psum += __shfl_xor(psum, 4);
    psum += __shfl_xor(psum, 8);  psum += __shfl_xor(psum, 16); psum += __shfl_xor(psum, 32);
    if (l == 0 && psum != 0.0f) atomicAdd(possum, psum);
}

// ---------------- kernel 3: final scalar ----------------
__global__ __launch_bounds__(512) void ntxent_final(const float* __restrict__ rowsum,
                                                    const float* __restrict__ possum,
                                                    float* __restrict__ out)
{
    __shared__ float sh[8];
    const int t = threadIdx.x;
    float s = 0.0f;
#pragma unroll
    for (int r = 0; r < 16; ++r) s += __logf(rowsum[r * 512 + t]);  // ILP: 16 indep loads
    s += __shfl_xor(s, 1);  s += __shfl_xor(s, 2);  s += __shfl_xor(s, 4);
    s += __shfl_xor(s, 8);  s += __shfl_xor(s, 16); s += __shfl_xor(s, 32);
    if ((t & 63) == 0) sh[t >> 6] = s;
    __syncthreads();
    if (t == 0) {
        float a = 0.0f;
#pragma unroll
        for (int k = 0; k < 8; ++k) a += sh[k];
        out[0] = (a - possum[0]) * (1.0f / NN);
    }
}

extern "C" void kernel_launch(void* const* d_in, const int* in_sizes, int n_in,
                              void* d_out, int out_size, void* d_ws, size_t ws_size,
                              hipStream_t stream)
{
    const float* z = (const float*)d_in[0];
    char*  znB    = (char*)d_ws;
    float* rowsum = (float*)((char*)d_ws + (size_t)NN * 512);
    float* possum = (float*)((char*)d_ws + (size_t)NN * 512 + (size_t)NN * 4);
    float* out = (float*)d_out;

    ntxent_norm <<<dim3(NN / 4), dim3(256), 0, stream>>>(z, znB, rowsum, possum);
    ntxent_sim  <<<dim3(NBLK),   dim3(512), 0, stream>>>(znB, rowsum, possum);
    ntxent_final<<<dim3(1),      dim3(512), 0, stream>>>(rowsum, possum, out);
}